// Round 4
// baseline (103.642 us; speedup 1.0000x reference)
//
#include <hip/hip_runtime.h>
#include <math.h>

#define D_DIM 128
#define K_DIM 64
#define R_DIM 8
#define B_DIM 8192
#define KG    4      // k-groups
#define KPB   16     // k per block (= waves per block)
#define ROWS  64     // b-rows per block (= lanes)
#define ENT   12     // floats per table entry: [w0..w7, -0.5*s_inv, h', 0, 0]

// ws layout (float offsets):
//   tbl : [K][D][ENT]   k-major, 48B/entry (s_load-friendly streams)
//   c0  : [K]
//   part: [B][KG][2]
#define WS_TBL  0
#define WS_C0   (K_DIM * D_DIM * ENT)
#define WS_PART (WS_C0 + K_DIM)

// ---------------------------------------------------------------------------
// Per-k precompute. Grid = K blocks, 128 threads (=D). Static-unrolled
// Cholesky (no scratch); q folded into h' and c0'.
// ---------------------------------------------------------------------------
__global__ __launch_bounds__(128) void precomp_kernel(
    const float* __restrict__ m, const float* __restrict__ delta,
    const float* __restrict__ U, const float* __restrict__ lar,
    float* __restrict__ ws) {
  const int k = blockIdx.x;
  const int d = threadIdx.x;  // 0..127

  __shared__ float U_l[D_DIM][R_DIM];
  __shared__ float V_l[D_DIM][R_DIM];
  __shared__ float W_l[D_DIM][R_DIM];
  __shared__ float m_l[D_DIM];
  __shared__ float red[64];
  __shared__ float Linv_s[R_DIM][R_DIM];
  __shared__ float q_s[R_DIM];
  __shared__ float c0_s[1];
  __shared__ float redA[D_DIM], redB[D_DIM], redC[D_DIM];

  const float dl    = delta[k * D_DIM + d];
  const float s_inv = expf(-dl);
  const float mv    = m[k * D_DIM + d];
  m_l[d] = mv;
  const float* Up = U + (size_t)(k * D_DIM + d) * R_DIM;
#pragma unroll
  for (int r = 0; r < R_DIM; ++r) {
    float u = Up[r];
    U_l[d][r] = u;
    V_l[d][r] = u * s_inv;
  }
  redA[d] = dl;
  redB[d] = mv * mv * s_inv;
  redC[d] = (d < K_DIM) ? lar[d] : 0.f;
  __syncthreads();

  if (d < 64) {
    const int r = d >> 3, s = d & 7;
    float acc = (r == s) ? 1.0f : 0.0f;
#pragma unroll 8
    for (int dd = 0; dd < D_DIM; ++dd) acc += U_l[dd][r] * V_l[dd][s];
    red[d] = acc;
  }
  __syncthreads();

  for (int off = 64; off > 0; off >>= 1) {
    if (d < off) {
      redA[d] += redA[d + off];
      redB[d] += redB[d + off];
      redC[d] += redC[d + off];
    }
    __syncthreads();
  }

  if (d == 0) {
    // 8x8 Cholesky, fully static after unroll
    float Lm[8][8];
#pragma unroll
    for (int i = 0; i < 8; ++i) {
#pragma unroll
      for (int j = 0; j < 8; ++j) {
        if (j > i) continue;
        float sum = red[i * 8 + j];
#pragma unroll
        for (int p = 0; p < 8; ++p)
          if (p < j) sum -= Lm[i][p] * Lm[j][p];
        if (i == j) Lm[i][i] = sqrtf(sum);
        else        Lm[i][j] = sum / Lm[j][j];
      }
    }
    float ld = 0.f;
#pragma unroll
    for (int i = 0; i < 8; ++i) ld += logf(Lm[i][i]);

    float Li[8][8];
#pragma unroll
    for (int i = 0; i < 8; ++i)
#pragma unroll
      for (int j = 0; j < 8; ++j) Li[i][j] = 0.f;
#pragma unroll
    for (int j = 0; j < 8; ++j) {
      Li[j][j] = 1.0f / Lm[j][j];
#pragma unroll
      for (int i = 0; i < 8; ++i) {
        if (i <= j) continue;
        float sum = 0.f;
#pragma unroll
        for (int p = 0; p < 8; ++p)
          if (p >= j && p < i) sum += Lm[i][p] * Li[p][j];
        Li[i][j] = -sum / Lm[i][i];
      }
    }
#pragma unroll
    for (int i = 0; i < 8; ++i)
#pragma unroll
      for (int j = 0; j < 8; ++j) Linv_s[i][j] = Li[i][j];

    const float mean = redC[0] * (1.0f / K_DIM);
    const float log_alpha = lar[k] - mean;       // /eps, eps=1
    const float logdetS = redA[0] + 2.0f * ld;
    const float LOG2PI = 1.8378770664093453f;
    const float log_norm = 0.5f * ((float)D_DIM * LOG2PI + logdetS);
    c0_s[0] = log_alpha - log_norm - 0.5f * redB[0];
  }
  __syncthreads();

  // W[d][r] = sum_{s<=r} V[d][s] * Linv[r][s]
  float Wr[R_DIM];
#pragma unroll
  for (int r = 0; r < R_DIM; ++r) {
    float acc = 0.f;
#pragma unroll
    for (int s2 = 0; s2 < R_DIM; ++s2)
      if (s2 <= r) acc += V_l[d][s2] * Linv_s[r][s2];
    Wr[r] = acc;
    W_l[d][r] = acc;
  }
  __syncthreads();

  // q[r] = sum_d W[d][r] * m[d]
  if (d < R_DIM) {
    float acc = 0.f;
#pragma unroll 8
    for (int dd = 0; dd < D_DIM; ++dd) acc += W_l[dd][d] * m_l[dd];
    q_s[d] = acc;
  }
  __syncthreads();

  // h' = m*s_inv - sum_r q_r * W_r
  float hp = mv * s_inv;
#pragma unroll
  for (int r = 0; r < R_DIM; ++r) hp -= q_s[r] * Wr[r];

  // k-major entry: wave k streams tbl[k][0..127][*] contiguously via s_load
  float* e = ws + WS_TBL + ((size_t)k * D_DIM + d) * ENT;
#pragma unroll
  for (int r = 0; r < R_DIM; ++r) e[r] = Wr[r];
  e[8]  = -0.5f * s_inv;
  e[9]  = hp;
  e[10] = 0.f;
  e[11] = 0.f;

  if (d == 0) {
    float qq = 0.f;
#pragma unroll
    for (int r = 0; r < R_DIM; ++r) qq += q_s[r] * q_s[r];
    ws[WS_C0 + k] = c0_s[0] + 0.5f * qq;   // c0' = c0 + 0.5*||q||^2
  }
}

// ---------------------------------------------------------------------------
// Main kernel: wave = one k (table via wave-uniform s_load, scalar pipe),
// lane = row (y from LDS, xor-swizzled b128, conflict-free). Block = 1024
// thr = 16 waves = 64 rows x 16 k. Grid = 128 rt x 4 kg = 512 blocks
// (2/CU, 32 waves/CU).
// ---------------------------------------------------------------------------
__global__ __launch_bounds__(1024, 8) void logz_main(
    const float* __restrict__ y, const float* __restrict__ ws,
    float* __restrict__ part) {
  __shared__ float4 sY[ROWS * 32];              // 32 KB, xor-swizzled
  __shared__ float vals[ROWS * (KPB + 1)];      // [row][k_local], stride 17

  const int tid  = threadIdx.x;
  const int lane = tid & 63;      // row within tile
  const int wv   = tid >> 6;      // 0..15 = k_local
  const int rt   = (int)blockIdx.x >> 2;
  const int kg   = (int)blockIdx.x & 3;
  const int r0   = rt * ROWS;

  // stage y tile: 2048 float4 slots, 2 per thread, coalesced global reads
  {
    const float4* ysrc = (const float4*)(y + (size_t)r0 * D_DIM);
#pragma unroll
    for (int j = 0; j < 2; ++j) {
      const int i   = tid + j * 1024;
      const int row = i >> 5, seg = i & 31;
      sY[row * 32 + (seg ^ (row & 7))] = ysrc[i];
    }
  }
  __syncthreads();

  // wave-uniform table pointer -> scalar loads
  const int k   = kg * KPB + wv;
  const int k_u = __builtin_amdgcn_readfirstlane(k);
  const float*  t  = ws + WS_TBL + (size_t)k_u * (D_DIM * ENT);
  const float4* t4 = (const float4*)t;
  const float2* t2 = (const float2*)t;

  const int swz = lane & 7;
  const float4* yrow = sY + lane * 32;

  float g = 0.f;
  float p0 = 0.f, p1 = 0.f, p2 = 0.f, p3 = 0.f;
  float p4 = 0.f, p5 = 0.f, p6 = 0.f, p7 = 0.f;

#pragma unroll 4
  for (int d4 = 0; d4 < D_DIM / 4; ++d4) {
    const float4 yv = yrow[d4 ^ swz];
#pragma unroll
    for (int j = 0; j < 4; ++j) {
      const int d = d4 * 4 + j;
      const float4 w0 = t4[d * 3];         // w0..w3   (SGPR)
      const float4 w1 = t4[d * 3 + 1];     // w4..w7   (SGPR)
      const float2 sh = t2[d * 6 + 4];     // (-0.5*s_inv, h')
      const float yd = (j == 0) ? yv.x : (j == 1) ? yv.y : (j == 2) ? yv.z : yv.w;
      g  = fmaf(yd, fmaf(sh.x, yd, sh.y), g);
      p0 = fmaf(yd, w0.x, p0);
      p1 = fmaf(yd, w0.y, p1);
      p2 = fmaf(yd, w0.z, p2);
      p3 = fmaf(yd, w0.w, p3);
      p4 = fmaf(yd, w1.x, p4);
      p5 = fmaf(yd, w1.y, p5);
      p6 = fmaf(yd, w1.z, p6);
      p7 = fmaf(yd, w1.w, p7);
    }
  }

  const float cv = ws[WS_C0 + k_u];
  const float qq = p0*p0 + p1*p1 + p2*p2 + p3*p3
                 + p4*p4 + p5*p5 + p6*p6 + p7*p7;
  const float val = cv + g + 0.5f * qq;

  vals[lane * (KPB + 1) + wv] = val;
  __syncthreads();

  if (tid < 64) {
    float mx = -INFINITY;
#pragma unroll
    for (int j = 0; j < KPB; ++j) mx = fmaxf(mx, vals[tid * (KPB + 1) + j]);
    float s = 0.f;
#pragma unroll
    for (int j = 0; j < KPB; ++j) s += expf(vals[tid * (KPB + 1) + j] - mx);
    *(float2*)(part + ((size_t)(r0 + tid) * KG + kg) * 2) = make_float2(mx, s);
  }
}

// ---------------------------------------------------------------------------
// Combine 4 kgroup-partials per b.
// ---------------------------------------------------------------------------
__global__ __launch_bounds__(256) void reduce_kernel(
    const float* __restrict__ part, float* __restrict__ out) {
  const int b = blockIdx.x * 256 + threadIdx.x;
  const float4 a0 = ((const float4*)part)[b * 2];
  const float4 a1 = ((const float4*)part)[b * 2 + 1];
  float mx = fmaxf(fmaxf(a0.x, a0.z), fmaxf(a1.x, a1.z));
  float s = a0.y * expf(a0.x - mx) + a0.w * expf(a0.z - mx)
          + a1.y * expf(a1.x - mx) + a1.w * expf(a1.z - mx);
  out[b] = mx + logf(s);
}

extern "C" void kernel_launch(void* const* d_in, const int* in_sizes, int n_in,
                              void* d_out, int out_size, void* d_ws, size_t ws_size,
                              hipStream_t stream) {
  const float* y     = (const float*)d_in[0];
  const float* m     = (const float*)d_in[1];
  const float* delta = (const float*)d_in[2];
  const float* U     = (const float*)d_in[3];
  const float* lar   = (const float*)d_in[4];
  float* out = (float*)d_out;
  float* ws  = (float*)d_ws;

  precomp_kernel<<<K_DIM, 128, 0, stream>>>(m, delta, U, lar, ws);
  logz_main<<<(B_DIM / ROWS) * KG, 1024, 0, stream>>>(y, ws, ws + WS_PART);
  reduce_kernel<<<B_DIM / 256, 256, 0, stream>>>(ws + WS_PART, out);
}

// Round 5
// 100.284 us; speedup vs baseline: 1.0335x; 1.0335x over previous
//
#include <hip/hip_runtime.h>
#include <math.h>

#define D_DIM 128
#define K_DIM 64
#define R_DIM 8
#define B_DIM 8192
#define KG    4      // k-groups
#define KPB   16     // k per block
#define ROWS  64     // b-rows per block
#define RPT   4      // rows per thread
#define CHUNK 32     // d per table LDS chunk
#define ENT   12     // floats per entry: [w0..w7 (scaled 1/sqrt2), -0.5*s_inv, h', 0, 0]

// ws layout (float offsets):
//   tbl : [KG][D][KPB][ENT] = 98304 floats
//   c0  : [K]
//   part: [B][KG][2]
#define WS_TBL  0
#define WS_C0   (KG * D_DIM * KPB * ENT)
#define WS_PART (WS_C0 + K_DIM)

// ---------------------------------------------------------------------------
// Per-k precompute (round-3 proven). Grid = K blocks, 128 threads (=D).
// Stored W scaled by 1/sqrt(2) so main kernel's ||p||^2 already includes 0.5.
// ---------------------------------------------------------------------------
__global__ __launch_bounds__(128) void precomp_kernel(
    const float* __restrict__ m, const float* __restrict__ delta,
    const float* __restrict__ U, const float* __restrict__ lar,
    float* __restrict__ ws) {
  const int k = blockIdx.x;
  const int d = threadIdx.x;  // 0..127

  __shared__ float U_l[D_DIM][R_DIM];
  __shared__ float V_l[D_DIM][R_DIM];
  __shared__ float W_l[D_DIM][R_DIM];
  __shared__ float m_l[D_DIM];
  __shared__ float red[64];
  __shared__ float Linv_s[R_DIM][R_DIM];
  __shared__ float q_s[R_DIM];
  __shared__ float c0_s[1];
  __shared__ float redA[D_DIM], redB[D_DIM], redC[D_DIM];

  const float dl    = delta[k * D_DIM + d];
  const float s_inv = expf(-dl);
  const float mv    = m[k * D_DIM + d];
  m_l[d] = mv;
  const float* Up = U + (size_t)(k * D_DIM + d) * R_DIM;
#pragma unroll
  for (int r = 0; r < R_DIM; ++r) {
    float u = Up[r];
    U_l[d][r] = u;
    V_l[d][r] = u * s_inv;
  }
  redA[d] = dl;
  redB[d] = mv * mv * s_inv;
  redC[d] = (d < K_DIM) ? lar[d] : 0.f;
  __syncthreads();

  if (d < 64) {
    const int r = d >> 3, s = d & 7;
    float acc = (r == s) ? 1.0f : 0.0f;
#pragma unroll 8
    for (int dd = 0; dd < D_DIM; ++dd) acc += U_l[dd][r] * V_l[dd][s];
    red[d] = acc;
  }
  __syncthreads();

  for (int off = 64; off > 0; off >>= 1) {
    if (d < off) {
      redA[d] += redA[d + off];
      redB[d] += redB[d + off];
      redC[d] += redC[d + off];
    }
    __syncthreads();
  }

  if (d == 0) {
    // 8x8 Cholesky, fully static after unroll
    float Lm[8][8];
#pragma unroll
    for (int i = 0; i < 8; ++i) {
#pragma unroll
      for (int j = 0; j < 8; ++j) {
        if (j > i) continue;
        float sum = red[i * 8 + j];
#pragma unroll
        for (int p = 0; p < 8; ++p)
          if (p < j) sum -= Lm[i][p] * Lm[j][p];
        if (i == j) Lm[i][i] = sqrtf(sum);
        else        Lm[i][j] = sum / Lm[j][j];
      }
    }
    float ld = 0.f;
#pragma unroll
    for (int i = 0; i < 8; ++i) ld += logf(Lm[i][i]);

    float Li[8][8];
#pragma unroll
    for (int i = 0; i < 8; ++i)
#pragma unroll
      for (int j = 0; j < 8; ++j) Li[i][j] = 0.f;
#pragma unroll
    for (int j = 0; j < 8; ++j) {
      Li[j][j] = 1.0f / Lm[j][j];
#pragma unroll
      for (int i = 0; i < 8; ++i) {
        if (i <= j) continue;
        float sum = 0.f;
#pragma unroll
        for (int p = 0; p < 8; ++p)
          if (p >= j && p < i) sum += Lm[i][p] * Li[p][j];
        Li[i][j] = -sum / Lm[i][i];
      }
    }
#pragma unroll
    for (int i = 0; i < 8; ++i)
#pragma unroll
      for (int j = 0; j < 8; ++j) Linv_s[i][j] = Li[i][j];

    const float mean = redC[0] * (1.0f / K_DIM);
    const float log_alpha = lar[k] - mean;       // /eps, eps=1
    const float logdetS = redA[0] + 2.0f * ld;
    const float LOG2PI = 1.8378770664093453f;
    const float log_norm = 0.5f * ((float)D_DIM * LOG2PI + logdetS);
    c0_s[0] = log_alpha - log_norm - 0.5f * redB[0];
  }
  __syncthreads();

  // W[d][r] = sum_{s<=r} V[d][s] * Linv[r][s]
  float Wr[R_DIM];
#pragma unroll
  for (int r = 0; r < R_DIM; ++r) {
    float acc = 0.f;
#pragma unroll
    for (int s2 = 0; s2 < R_DIM; ++s2)
      if (s2 <= r) acc += V_l[d][s2] * Linv_s[r][s2];
    Wr[r] = acc;
    W_l[d][r] = acc;
  }
  __syncthreads();

  // q[r] = sum_d W[d][r] * m[d]
  if (d < R_DIM) {
    float acc = 0.f;
#pragma unroll 8
    for (int dd = 0; dd < D_DIM; ++dd) acc += W_l[dd][d] * m_l[dd];
    q_s[d] = acc;
  }
  __syncthreads();

  // h' = m*s_inv - sum_r q_r * W_r   (uses UNSCALED W)
  float hp = mv * s_inv;
#pragma unroll
  for (int r = 0; r < R_DIM; ++r) hp -= q_s[r] * Wr[r];

  const float INV_SQRT2 = 0.70710678118654752f;
  float* e = ws + WS_TBL +
             (size_t)(((k >> 4) * D_DIM + d) * KPB + (k & 15)) * ENT;
#pragma unroll
  for (int r = 0; r < R_DIM; ++r) e[r] = Wr[r] * INV_SQRT2;
  e[8]  = -0.5f * s_inv;
  e[9]  = hp;
  e[10] = 0.f;
  e[11] = 0.f;

  if (d == 0) {
    float qq = 0.f;
#pragma unroll
    for (int r = 0; r < R_DIM; ++r) qq += q_s[r] * q_s[r];
    ws[WS_C0 + k] = c0_s[0] + 0.5f * qq;   // c0' = c0 + 0.5*||q||^2
  }
}

// ---------------------------------------------------------------------------
// Main kernel: block = 256 thr = 4 waves; lane = 16 ki x 4 bi; each thread
// 4 rows (bi + 4j within its wave's 16-row group) -> block = 64 rows x 16 k.
// Table reads amortized over 4 rows; y staged once (float4 stride 33 ->
// the 4-distinct-row b128 reads land on disjoint banks). Grid = 128 rt x
// 4 kg = 512 blocks (2/CU, 8 waves/CU).
// ---------------------------------------------------------------------------
__global__ __launch_bounds__(256, 2) void logz_main(
    const float* __restrict__ y, const float* __restrict__ ws,
    float* __restrict__ part) {
  __shared__ float4 sY4[ROWS * 33];            // 33792 B, row stride 33
  __shared__ float  sT[CHUNK * KPB * ENT];     // 24576 B, [dl][ki][ENT]
  __shared__ float  vals[ROWS * (KPB + 1)];    // [row][ki], stride 17

  const int tid  = threadIdx.x;                // 0..255
  const int lane = tid & 63;
  const int wv   = tid >> 6;                   // 0..3
  const int ki   = lane & 15;
  const int bi   = lane >> 4;                  // 0..3
  const int rt   = (int)blockIdx.x >> 2;
  const int kg   = (int)blockIdx.x & 3;
  const int r0   = rt * ROWS;
  const int rowb = wv * 16 + bi;               // thread rows: rowb + 4j

  // stage y tile once: 2048 float4, 8 per thread, coalesced
  {
    const float4* ysrc = (const float4*)(y + (size_t)r0 * D_DIM);
#pragma unroll
    for (int j = 0; j < 8; ++j) {
      const int idx = tid + j * 256;
      sY4[(idx >> 5) * 33 + (idx & 31)] = ysrc[idx];
    }
  }

  const float* __restrict__ tblG = ws + WS_TBL + (size_t)kg * (D_DIM * KPB * ENT);

  float g[RPT];
  float p[RPT][8];
#pragma unroll
  for (int j = 0; j < RPT; ++j) {
    g[j] = 0.f;
#pragma unroll
    for (int r = 0; r < 8; ++r) p[j][r] = 0.f;
  }

  for (int c = 0; c < D_DIM / CHUNK; ++c) {
    __syncthreads();   // prev chunk's compute done (also covers y-stage on c=0)
    // stage table chunk (24 KB): each of 4 waves copies 6 x 1KB
    {
      const float* src = tblG + (size_t)c * (CHUNK * KPB * ENT);
#pragma unroll
      for (int j = 0; j < 6; ++j) {
        const int off = (wv * 6 + j) * 256;   // floats
        __builtin_amdgcn_global_load_lds(
            (const __attribute__((address_space(1))) void*)(src + off + lane * 4),
            (__attribute__((address_space(3))) void*)(sT + off),
            16, 0, 0);
      }
    }
    __syncthreads();

#pragma unroll
    for (int d4 = 0; d4 < CHUNK / 4; ++d4) {
      float4 yv[RPT];
#pragma unroll
      for (int j = 0; j < RPT; ++j)
        yv[j] = sY4[(rowb + 4 * j) * 33 + c * (CHUNK / 4) + d4];
#pragma unroll
      for (int dj = 0; dj < 4; ++dj) {
        const float* e = sT + ((d4 * 4 + dj) * KPB + ki) * ENT;
        const float4 w0 = *(const float4*)(e);
        const float4 w1 = *(const float4*)(e + 4);
        const float2 sh = *(const float2*)(e + 8);   // (-0.5*s_inv, h')
#pragma unroll
        for (int j = 0; j < RPT; ++j) {
          const float yd = (dj == 0) ? yv[j].x : (dj == 1) ? yv[j].y
                         : (dj == 2) ? yv[j].z : yv[j].w;
          g[j]    = fmaf(yd, fmaf(sh.x, yd, sh.y), g[j]);
          p[j][0] = fmaf(yd, w0.x, p[j][0]);
          p[j][1] = fmaf(yd, w0.y, p[j][1]);
          p[j][2] = fmaf(yd, w0.z, p[j][2]);
          p[j][3] = fmaf(yd, w0.w, p[j][3]);
          p[j][4] = fmaf(yd, w1.x, p[j][4]);
          p[j][5] = fmaf(yd, w1.y, p[j][5]);
          p[j][6] = fmaf(yd, w1.z, p[j][6]);
          p[j][7] = fmaf(yd, w1.w, p[j][7]);
        }
      }
    }
  }

  const float cv = ws[WS_C0 + kg * KPB + ki];
#pragma unroll
  for (int j = 0; j < RPT; ++j) {
    // W pre-scaled by 1/sqrt(2): ||p||^2 already includes the 0.5 factor
    const float qq = p[j][0]*p[j][0] + p[j][1]*p[j][1] + p[j][2]*p[j][2]
                   + p[j][3]*p[j][3] + p[j][4]*p[j][4] + p[j][5]*p[j][5]
                   + p[j][6]*p[j][6] + p[j][7]*p[j][7];
    vals[(rowb + 4 * j) * (KPB + 1) + ki] = cv + g[j] + qq;
  }
  __syncthreads();

  if (tid < 64) {
    float mx = -INFINITY;
#pragma unroll
    for (int j = 0; j < KPB; ++j) mx = fmaxf(mx, vals[tid * (KPB + 1) + j]);
    float s = 0.f;
#pragma unroll
    for (int j = 0; j < KPB; ++j) s += expf(vals[tid * (KPB + 1) + j] - mx);
    *(float2*)(part + ((size_t)(r0 + tid) * KG + kg) * 2) = make_float2(mx, s);
  }
}

// ---------------------------------------------------------------------------
// Combine 4 kgroup-partials per b.
// ---------------------------------------------------------------------------
__global__ __launch_bounds__(256) void reduce_kernel(
    const float* __restrict__ part, float* __restrict__ out) {
  const int b = blockIdx.x * 256 + threadIdx.x;
  const float4 a0 = ((const float4*)part)[b * 2];
  const float4 a1 = ((const float4*)part)[b * 2 + 1];
  float mx = fmaxf(fmaxf(a0.x, a0.z), fmaxf(a1.x, a1.z));
  float s = a0.y * expf(a0.x - mx) + a0.w * expf(a0.z - mx)
          + a1.y * expf(a1.x - mx) + a1.w * expf(a1.z - mx);
  out[b] = mx + logf(s);
}

extern "C" void kernel_launch(void* const* d_in, const int* in_sizes, int n_in,
                              void* d_out, int out_size, void* d_ws, size_t ws_size,
                              hipStream_t stream) {
  const float* y     = (const float*)d_in[0];
  const float* m     = (const float*)d_in[1];
  const float* delta = (const float*)d_in[2];
  const float* U     = (const float*)d_in[3];
  const float* lar   = (const float*)d_in[4];
  float* out = (float*)d_out;
  float* ws  = (float*)d_ws;

  precomp_kernel<<<K_DIM, 128, 0, stream>>>(m, delta, U, lar, ws);
  logz_main<<<(B_DIM / ROWS) * KG, 256, 0, stream>>>(y, ws, ws + WS_PART);
  reduce_kernel<<<B_DIM / 256, 256, 0, stream>>>(ws + WS_PART, out);
}

// Round 6
// 81.542 us; speedup vs baseline: 1.2710x; 1.2298x over previous
//
#include <hip/hip_runtime.h>
#include <math.h>

#define D_DIM 128
#define K_DIM 64
#define R_DIM 8
#define B_DIM 8192
#define KG    4          // k-groups (16 k each)
#define XSTR  264        // bf16 per staged X row (256 data + 8 pad)
#define ESTR  161        // floats per epilogue row
#define TCH   5120       // bf16 per T chunk: 160 cols x 32 k

// ws layout:
//   T   : bf16 [KG][8 chunks][160 cols][32 k]   = 163840 ushort = 81920 floats
//   c0  : float [K]        at float offset 81920
//   part: float [B][KG][2] at float offset 81984
#define WS_C0F   81920
#define WS_PARTF 81984

typedef __bf16 bf16x8 __attribute__((ext_vector_type(8)));
typedef float  f32x4  __attribute__((ext_vector_type(4)));

static __device__ inline unsigned short f2bf(float f) {
  union { float f; unsigned int u; } v; v.f = f;
  unsigned int u = v.u;
  unsigned int lsb = (u >> 16) & 1;
  u += 0x7fffu + lsb;                 // round-to-nearest-even
  return (unsigned short)(u >> 16);
}

// ---------------------------------------------------------------------------
// Per-k precompute (r3-proven math). Grid = K blocks, 128 threads (=D).
// Output: bf16 table in B-fragment-ready layout [kg][chunk][col][32k]:
//   per k, 10 cols: 0..7 = W/sqrt2 (y-part; zero in y^2-part),
//   col 8 = h' (y-part) and -0.5*s_inv (y^2-part), col 9 = pad zeros.
// ---------------------------------------------------------------------------
__global__ __launch_bounds__(128) void precomp_kernel(
    const float* __restrict__ m, const float* __restrict__ delta,
    const float* __restrict__ U, const float* __restrict__ lar,
    float* __restrict__ ws) {
  const int k = blockIdx.x;
  const int d = threadIdx.x;  // 0..127

  __shared__ float U_l[D_DIM][R_DIM];
  __shared__ float V_l[D_DIM][R_DIM];
  __shared__ float W_l[D_DIM][R_DIM];
  __shared__ float m_l[D_DIM];
  __shared__ float red[64];
  __shared__ float Linv_s[R_DIM][R_DIM];
  __shared__ float q_s[R_DIM];
  __shared__ float c0_s[1];
  __shared__ float redA[D_DIM], redB[D_DIM], redC[D_DIM];

  const float dl    = delta[k * D_DIM + d];
  const float s_inv = expf(-dl);
  const float mv    = m[k * D_DIM + d];
  m_l[d] = mv;
  const float* Up = U + (size_t)(k * D_DIM + d) * R_DIM;
#pragma unroll
  for (int r = 0; r < R_DIM; ++r) {
    float u = Up[r];
    U_l[d][r] = u;
    V_l[d][r] = u * s_inv;
  }
  redA[d] = dl;
  redB[d] = mv * mv * s_inv;
  redC[d] = (d < K_DIM) ? lar[d] : 0.f;
  __syncthreads();

  if (d < 64) {
    const int r = d >> 3, s = d & 7;
    float acc = (r == s) ? 1.0f : 0.0f;
#pragma unroll 8
    for (int dd = 0; dd < D_DIM; ++dd) acc += U_l[dd][r] * V_l[dd][s];
    red[d] = acc;
  }
  __syncthreads();

  for (int off = 64; off > 0; off >>= 1) {
    if (d < off) {
      redA[d] += redA[d + off];
      redB[d] += redB[d + off];
      redC[d] += redC[d + off];
    }
    __syncthreads();
  }

  if (d == 0) {
    float Lm[8][8];
#pragma unroll
    for (int i = 0; i < 8; ++i) {
#pragma unroll
      for (int j = 0; j < 8; ++j) {
        if (j > i) continue;
        float sum = red[i * 8 + j];
#pragma unroll
        for (int p = 0; p < 8; ++p)
          if (p < j) sum -= Lm[i][p] * Lm[j][p];
        if (i == j) Lm[i][i] = sqrtf(sum);
        else        Lm[i][j] = sum / Lm[j][j];
      }
    }
    float ld = 0.f;
#pragma unroll
    for (int i = 0; i < 8; ++i) ld += logf(Lm[i][i]);

    float Li[8][8];
#pragma unroll
    for (int i = 0; i < 8; ++i)
#pragma unroll
      for (int j = 0; j < 8; ++j) Li[i][j] = 0.f;
#pragma unroll
    for (int j = 0; j < 8; ++j) {
      Li[j][j] = 1.0f / Lm[j][j];
#pragma unroll
      for (int i = 0; i < 8; ++i) {
        if (i <= j) continue;
        float sum = 0.f;
#pragma unroll
        for (int p = 0; p < 8; ++p)
          if (p >= j && p < i) sum += Lm[i][p] * Li[p][j];
        Li[i][j] = -sum / Lm[i][i];
      }
    }
#pragma unroll
    for (int i = 0; i < 8; ++i)
#pragma unroll
      for (int j = 0; j < 8; ++j) Linv_s[i][j] = Li[i][j];

    const float mean = redC[0] * (1.0f / K_DIM);
    const float log_alpha = lar[k] - mean;       // /eps, eps=1
    const float logdetS = redA[0] + 2.0f * ld;
    const float LOG2PI = 1.8378770664093453f;
    const float log_norm = 0.5f * ((float)D_DIM * LOG2PI + logdetS);
    c0_s[0] = log_alpha - log_norm - 0.5f * redB[0];
  }
  __syncthreads();

  float Wr[R_DIM];
#pragma unroll
  for (int r = 0; r < R_DIM; ++r) {
    float acc = 0.f;
#pragma unroll
    for (int s2 = 0; s2 < R_DIM; ++s2)
      if (s2 <= r) acc += V_l[d][s2] * Linv_s[r][s2];
    Wr[r] = acc;
    W_l[d][r] = acc;
  }
  __syncthreads();

  if (d < R_DIM) {
    float acc = 0.f;
#pragma unroll 8
    for (int dd = 0; dd < D_DIM; ++dd) acc += W_l[dd][d] * m_l[dd];
    q_s[d] = acc;
  }
  __syncthreads();

  float hp = mv * s_inv;
#pragma unroll
  for (int r = 0; r < R_DIM; ++r) hp -= q_s[r] * Wr[r];

  // ---- bf16 table writes (B-fragment-ready layout) ----
  const float INV_SQRT2 = 0.70710678118654752f;
  unsigned short* T = (unsigned short*)ws;
  const int kg = k >> 4, kl = k & 15;
  const int chunk = d >> 5, pos = d & 31;
  const size_t base_y = (((size_t)kg * 8 + chunk) * 160) * 32;
  const size_t base_q = (((size_t)kg * 8 + 4 + chunk) * 160) * 32;
#pragma unroll
  for (int c = 0; c < 8; ++c) {
    T[base_y + (size_t)(kl * 10 + c) * 32 + pos] = f2bf(Wr[c] * INV_SQRT2);
    T[base_q + (size_t)(kl * 10 + c) * 32 + pos] = 0;   // y^2-part W cols = 0
  }
  T[base_y + (size_t)(kl * 10 + 8) * 32 + pos] = f2bf(hp);
  T[base_q + (size_t)(kl * 10 + 8) * 32 + pos] = f2bf(-0.5f * s_inv);
  T[base_y + (size_t)(kl * 10 + 9) * 32 + pos] = 0;     // pad col
  T[base_q + (size_t)(kl * 10 + 9) * 32 + pos] = 0;

  if (d == 0) {
    float qq = 0.f;
#pragma unroll
    for (int r = 0; r < R_DIM; ++r) qq += q_s[r] * q_s[r];
    ws[WS_C0F + k] = c0_s[0] + 0.5f * qq;   // c0' = c0 + 0.5*||q||^2
  }
}

// ---------------------------------------------------------------------------
// MFMA main kernel. Block = 256 thr = 4 waves (2x2 over 32 rows x 160 cols).
// X = [bf16(y), bf16(y^2)] staged in LDS; T chunks staged 2-at-a-time via
// global_load_lds (contiguous, pre-laid). 8 K-iters of mfma_16x16x32_bf16.
// Epilogue: square/add via LDS, logsumexp over 16 k -> part.
// Grid = 256 rowtiles x 4 kg = 1024 blocks (4/CU).
// ---------------------------------------------------------------------------
__global__ __launch_bounds__(256, 4) void logz_main(
    const float* __restrict__ y, const float* __restrict__ ws,
    float* __restrict__ part) {
  __shared__ __align__(16) unsigned short sX[32 * XSTR];   // 16896 B
  __shared__ __align__(16) float sbuf[32 * ESTR];          // 20608 B (T chunks / evals)
  __shared__ float vals2[32 * 17];

  const int tid   = threadIdx.x;            // 0..255
  const int lane  = tid & 63;
  const int wv    = tid >> 6;               // 0..3
  const int wr    = wv >> 1;                // row-wave 0..1
  const int wc    = wv & 1;                 // col-wave 0..1
  const int col_l = lane & 15;
  const int quad  = lane >> 4;
  const int rt    = (int)blockIdx.x >> 2;
  const int kg    = (int)blockIdx.x & 3;

  // ---- stage X = [y, y^2] as bf16, 32 rows ----
  {
    const float4* yb = (const float4*)(y + (size_t)rt * 32 * D_DIM);
#pragma unroll
    for (int j = 0; j < 4; ++j) {
      const int idx = tid + j * 256;        // 1024 float4 total
      const int row = idx >> 5, seg = idx & 31;
      const float4 v = yb[idx];
      unsigned short* px = sX + row * XSTR + seg * 4;
      px[0] = f2bf(v.x); px[1] = f2bf(v.y);
      px[2] = f2bf(v.z); px[3] = f2bf(v.w);
      unsigned short* pq = px + 128;
      pq[0] = f2bf(v.x * v.x); pq[1] = f2bf(v.y * v.y);
      pq[2] = f2bf(v.z * v.z); pq[3] = f2bf(v.w * v.w);
    }
  }

  f32x4 acc[5];
#pragma unroll
  for (int f = 0; f < 5; ++f) { acc[f][0] = 0.f; acc[f][1] = 0.f; acc[f][2] = 0.f; acc[f][3] = 0.f; }

  const float* tG = ws + (size_t)kg * 8 * (TCH / 2);   // float units
  unsigned short* sT = (unsigned short*)sbuf;

  for (int pair = 0; pair < 4; ++pair) {
    __syncthreads();   // prev pair's compute done (covers X-stage on pair 0)
    // stage chunks 2*pair, 2*pair+1 : 20480 B = 20 x 1KB insts, 5 per wave
    {
      const float* src = tG + (size_t)pair * TCH;      // 2 chunks = 5120 floats
#pragma unroll
      for (int j = 0; j < 5; ++j) {
        const int off = (wv * 5 + j) * 256;            // floats
        __builtin_amdgcn_global_load_lds(
            (const __attribute__((address_space(1))) void*)(src + off + lane * 4),
            (__attribute__((address_space(3))) void*)((float*)sbuf + off),
            16, 0, 0);
      }
    }
    __syncthreads();
#pragma unroll
    for (int ii = 0; ii < 2; ++ii) {
      const int kiter = pair * 2 + ii;
      const bf16x8 a = *(const bf16x8*)(sX + (wr * 16 + col_l) * XSTR
                                          + kiter * 32 + quad * 8);
      const unsigned short* cb = sT + ii * TCH;
#pragma unroll
      for (int f = 0; f < 5; ++f) {
        const bf16x8 b = *(const bf16x8*)(cb + (wc * 80 + f * 16 + col_l) * 32
                                             + quad * 8);
        acc[f] = __builtin_amdgcn_mfma_f32_16x16x32_bf16(a, b, acc[f], 0, 0, 0);
      }
    }
  }

  __syncthreads();   // all MFMA LDS reads done; reuse sbuf as evals
  float* evals = sbuf;
#pragma unroll
  for (int f = 0; f < 5; ++f) {
    const int col = wc * 80 + f * 16 + col_l;
    const int c10 = col % 10;
#pragma unroll
    for (int reg = 0; reg < 4; ++reg) {
      const float v = acc[f][reg];
      evals[(wr * 16 + quad * 4 + reg) * ESTR + col] = (c10 == 8) ? v : v * v;
    }
  }
  __syncthreads();

  // per (row, k): 512 pairs, 2 per thread
  const float* c0p = ws + WS_C0F + kg * 16;
#pragma unroll
  for (int j = 0; j < 2; ++j) {
    const int idx = tid + j * 256;
    const int row = idx >> 4, kl = idx & 15;
    const float* e = evals + row * ESTR + kl * 10;
    float s = c0p[kl] + e[8];
#pragma unroll
    for (int c = 0; c < 8; ++c) s += e[c];
    vals2[row * 17 + kl] = s;
  }
  __syncthreads();

  if (tid < 32) {
    const int row = tid;
    float mx = -INFINITY;
#pragma unroll
    for (int j = 0; j < 16; ++j) mx = fmaxf(mx, vals2[row * 17 + j]);
    float s = 0.f;
#pragma unroll
    for (int j = 0; j < 16; ++j) s += expf(vals2[row * 17 + j] - mx);
    *(float2*)(part + ((size_t)(rt * 32 + row) * KG + kg) * 2) = make_float2(mx, s);
  }
}

// ---------------------------------------------------------------------------
// Combine 4 kgroup-partials per b.
// ---------------------------------------------------------------------------
__global__ __launch_bounds__(256) void reduce_kernel(
    const float* __restrict__ part, float* __restrict__ out) {
  const int b = blockIdx.x * 256 + threadIdx.x;
  const float4 a0 = ((const float4*)part)[b * 2];
  const float4 a1 = ((const float4*)part)[b * 2 + 1];
  float mx = fmaxf(fmaxf(a0.x, a0.z), fmaxf(a1.x, a1.z));
  float s = a0.y * expf(a0.x - mx) + a0.w * expf(a0.z - mx)
          + a1.y * expf(a1.x - mx) + a1.w * expf(a1.z - mx);
  out[b] = mx + logf(s);
}

extern "C" void kernel_launch(void* const* d_in, const int* in_sizes, int n_in,
                              void* d_out, int out_size, void* d_ws, size_t ws_size,
                              hipStream_t stream) {
  const float* y     = (const float*)d_in[0];
  const float* m     = (const float*)d_in[1];
  const float* delta = (const float*)d_in[2];
  const float* U     = (const float*)d_in[3];
  const float* lar   = (const float*)d_in[4];
  float* out = (float*)d_out;
  float* ws  = (float*)d_ws;

  precomp_kernel<<<K_DIM, 128, 0, stream>>>(m, delta, U, lar, ws);
  logz_main<<<(B_DIM / 32) * KG, 256, 0, stream>>>(y, ws, ws + WS_PARTF);
  reduce_kernel<<<B_DIM / 256, 256, 0, stream>>>(ws + WS_PARTF, out);
}